// Round 1
// baseline (320.137 us; speedup 1.0000x reference)
//
#include <hip/hip_runtime.h>

#define IMG_H 4096
#define IMG_W 4096
#define RAD 4
#define TSX 32
#define TSY 32
#define LROWS (TSY + 2*RAD)   // 40
#define LCOLS (TSX + 2*RAD)   // 40
#define LSTRIDE 44            // pad row stride to multiple of 4 floats -> 16B-aligned rows

__device__ __forceinline__ int reflect_idx(int i, int n) {
    i = (i < 0) ? -i : i;
    i = (i >= n) ? (2 * n - 2 - i) : i;
    return i;
}

__global__ __launch_bounds__(256) void bilateral_kernel(const float* __restrict__ in,
                                                        float* __restrict__ out) {
    __shared__ float tile[LROWS][LSTRIDE];
    const int bx = blockIdx.x * TSX;
    const int by = blockIdx.y * TSY;
    const int tid = threadIdx.x;

    // Stage (40x40) input window (with reflect at borders) into LDS.
    for (int i = tid; i < LROWS * LCOLS; i += 256) {
        int ly = i / LCOLS;
        int lx = i - ly * LCOLS;
        int gy = reflect_idx(by + ly - RAD, IMG_H);
        int gx = reflect_idx(bx + lx - RAD, IMG_W);
        tile[ly][lx] = in[gy * IMG_W + gx];
    }
    __syncthreads();

    // 256 threads = 8 x-threads (4 px each) x 32 rows -> 32x32 outputs per block.
    const int tx = tid & 7;
    const int ty = tid >> 3;
    const int x0 = tx * 4;

    constexpr float LOG2E = 1.4426950408889634f;
    constexpr float KR = -50.0f * LOG2E;  // -log2e / (2*sigma_r^2), sigma_r=0.1

    float num[4] = {0.f, 0.f, 0.f, 0.f};
    float den[4] = {0.f, 0.f, 0.f, 0.f};
    float ctr[4];
#pragma unroll
    for (int p = 0; p < 4; ++p) ctr[p] = tile[ty + RAD][x0 + RAD + p];

#pragma unroll
    for (int dy = 0; dy < 9; ++dy) {
        const float* rowp = &tile[ty + dy][x0];
        float4 va = *reinterpret_cast<const float4*>(rowp);
        float4 vb = *reinterpret_cast<const float4*>(rowp + 4);
        float4 vc = *reinterpret_cast<const float4*>(rowp + 8);
        float v[12] = {va.x, va.y, va.z, va.w,
                       vb.x, vb.y, vb.z, vb.w,
                       vc.x, vc.y, vc.z, vc.w};
#pragma unroll
        for (int dx = 0; dx < 9; ++dx) {
            const int ddx = dx - RAD, ddy = dy - RAD;
            // log2(spatial weight): -(ddx^2+ddy^2)/18 * log2e  (compile-time constant)
            const float sc = -(float)(ddx * ddx + ddy * ddy) * (LOG2E / 18.0f);
#pragma unroll
            for (int p = 0; p < 4; ++p) {
                float win = v[dx + p];
                float diff = win - ctr[p];
                float w = __builtin_amdgcn_exp2f(fmaf(diff * KR, diff, sc));
                num[p] = fmaf(w, win, num[p]);
                den[p] += w;
            }
        }
    }

    float4 o;
    o.x = num[0] / den[0];
    o.y = num[1] / den[1];
    o.z = num[2] / den[2];
    o.w = num[3] / den[3];
    *reinterpret_cast<float4*>(&out[(by + ty) * IMG_W + bx + x0]) = o;
}

extern "C" void kernel_launch(void* const* d_in, const int* in_sizes, int n_in,
                              void* d_out, int out_size, void* d_ws, size_t ws_size,
                              hipStream_t stream) {
    const float* in = (const float*)d_in[0];
    float* out = (float*)d_out;
    dim3 grid(IMG_W / TSX, IMG_H / TSY);
    bilateral_kernel<<<grid, 256, 0, stream>>>(in, out);
}